// Round 9
// baseline (332.318 us; speedup 1.0000x reference)
//
#include <hip/hip_runtime.h>
#include <hip/hip_bf16.h>
#include <hip/hip_cooperative_groups.h>

// ---------- constants (problem-fixed) ----------
#define NNODES 10000
#define NEDGES 80000
#define OBS    128
#define HID    1024
#define ACTD   8
#define NGR    64
#define NB     256            // grid blocks (1 per CU, co-resident)
#define NT     512            // threads per block (8 waves)

namespace cg = cooperative_groups;

typedef __bf16 bf16x8 __attribute__((ext_vector_type(8)));
typedef float  f32x4  __attribute__((ext_vector_type(4)));
typedef const __attribute__((address_space(1))) unsigned int gl_u32;
typedef __attribute__((address_space(3))) unsigned int lds_u32;

__device__ __forceinline__ ushort f2b(float f) {       // f32 -> bf16 (RNE)
    union { float f; unsigned int i; } v; v.f = f;
    unsigned int lsb = (v.i >> 16) & 1u;
    unsigned int r = v.i + 0x7fffu + lsb;
    return (ushort)(r >> 16);
}
__device__ __forceinline__ int cix(int v, int hi) {    // clamp index to [0, hi)
    return v < 0 ? 0 : (v >= hi ? hi - 1 : v);
}

struct MegaArgs {
    const float* x; const int* src; const int* dst; const int* bat;
    const float* W1; const float* b1; const float* W2; const float* b2;
    const float* Wl; const float* bl;
    float* out;
    float* pool; float* cnt; float* zacc; int* degi;     // zeroed by memset
    float* dinv; int* rowptr; int* cursor; int* esrc; float* coefs;
    float* b2l; ushort* M2bf; ushort* Wt1; ushort* aggbf;
};

__global__ __launch_bounds__(NT, 2) void k_mega(MegaArgs a) {
    cg::grid_group grid = cg::this_grid();
    __shared__ ushort buf[128 * 136 + 16 * 128];         // 38912 B, reused per phase
    const int blk = blockIdx.x, t = threadIdx.x;
    const int lane = t & 63, wv = t >> 6;

    // ===== Phase A: degree count | W1 transpose | M2 = W2@Wl (+b2l) =====
    if (blk < 64) {
        for (int i = blk * NT + t; i < NEDGES; i += 64 * NT)
            atomicAdd(&a.degi[cix(a.dst[i], NNODES)], 1);
    } else if (blk < 192) {
        float* tile = (float*)buf;                       // [32][33]
        int b2i = blk - 64;
        int bx = (b2i & 31) * 32, by = (b2i >> 5) * 32;  // bx over HID, by over OBS
        int tx = t & 31, ty = t >> 5;                    // ty 0..15
        #pragma unroll
        for (int i = 0; i < 32; i += 16)
            tile[(ty + i) * 33 + tx] = a.W1[(size_t)(by + ty + i) * HID + bx + tx];
        __syncthreads();
        #pragma unroll
        for (int i = 0; i < 32; i += 16)
            a.Wt1[(size_t)(bx + ty + i) * OBS + by + tx] = f2b(tile[tx * 33 + ty + i]);
    } else {
        int w0 = (blk - 192) * 8 + wv;                   // 0..511
        for (int r = w0; r <= HID; r += 512) {
            const float* row = (r == HID) ? a.b2 : (a.W2 + (size_t)r * HID);
            float acc[ACTD];
            #pragma unroll
            for (int j = 0; j < ACTD; ++j) acc[j] = 0.0f;
            for (int it = 0; it < HID / 64; ++it) {
                int k = it * 64 + lane;
                float w2v = row[k];
                float4 p = *(const float4*)(a.Wl + (size_t)k * ACTD);
                float4 q = *(const float4*)(a.Wl + (size_t)k * ACTD + 4);
                acc[0] += w2v * p.x; acc[1] += w2v * p.y; acc[2] += w2v * p.z; acc[3] += w2v * p.w;
                acc[4] += w2v * q.x; acc[5] += w2v * q.y; acc[6] += w2v * q.z; acc[7] += w2v * q.w;
            }
            #pragma unroll
            for (int off = 32; off > 0; off >>= 1)
                #pragma unroll
                for (int j = 0; j < ACTD; ++j)
                    acc[j] += __shfl_down(acc[j], off);
            if (lane == 0) {
                if (r == HID) {
                    #pragma unroll
                    for (int j = 0; j < ACTD; ++j) a.b2l[j] = acc[j] + a.bl[j];
                } else {
                    #pragma unroll
                    for (int j = 0; j < ACTD; ++j) a.M2bf[r * ACTD + j] = f2b(acc[j]);
                }
            }
        }
    }
    grid.sync();

    // ===== Phase B: scan -> rowptr/cursor (+dinv), block 0 only =====
    if (blk == 0) {
        int* wsum = (int*)buf;                           // 8 ints
        int base = t * 20;                               // 512*20 = 10240 >= N
        int local[20];
        int s = 0;
        #pragma unroll
        for (int k = 0; k < 20; ++k) {
            int i = base + k;
            int v = 0;
            if (i < NNODES) {
                v = a.degi[i];
                a.dinv[i] = rsqrtf((float)(v + 1));      // +1 self-loop
            }
            local[k] = s; s += v;
        }
        int sc = s;                                      // inclusive wave scan
        #pragma unroll
        for (int off = 1; off < 64; off <<= 1) {
            int u = __shfl_up(sc, off);
            if (lane >= off) sc += u;
        }
        if (lane == 63) wsum[wv] = sc;
        __syncthreads();
        if (wv == 0 && lane < 8) {
            int v = wsum[lane];
            #pragma unroll
            for (int off = 1; off < 8; off <<= 1) {
                int u = __shfl_up(v, off);
                if (lane >= off) v += u;
            }
            wsum[lane] = v;
        }
        __syncthreads();
        int excl = ((wv == 0) ? 0 : wsum[wv - 1]) + (sc - s);
        #pragma unroll
        for (int k = 0; k < 20; ++k) {
            int i = base + k;
            if (i < NNODES) { a.rowptr[i] = excl + local[k]; a.cursor[i] = excl + local[k]; }
        }
        if (t == 0) a.rowptr[NNODES] = wsum[7];
    }
    grid.sync();

    // ===== Phase C: CSR fill (bucket by dst) =====
    for (int i = blk * NT + t; i < NEDGES; i += NB * NT) {
        int s = cix(a.src[i], NNODES), d = cix(a.dst[i], NNODES);
        int pos = atomicAdd(&a.cursor[d], 1);
        a.esrc[pos] = s;
        a.coefs[pos] = a.dinv[s] * a.dinv[d];
    }
    grid.sync();

    // ===== Phase D: layer-1 aggregation (CSR gather, wave per node) -> bf16 =====
    for (int nd = blk * 8 + wv; nd < NNODES; nd += NB * 8) {
        float d = a.dinv[nd], d2 = d * d;
        float2 xv = *(const float2*)(a.x + (size_t)nd * OBS + lane * 2);
        float v0 = xv.x * d2, v1 = xv.y * d2;
        int e = a.rowptr[nd], e1 = a.rowptr[nd + 1];
        for (; e + 2 <= e1; e += 2) {
            int s0 = a.esrc[e], s1 = a.esrc[e + 1];
            float c0 = a.coefs[e], c1 = a.coefs[e + 1];
            float2 p = *(const float2*)(a.x + (size_t)s0 * OBS + lane * 2);
            float2 q = *(const float2*)(a.x + (size_t)s1 * OBS + lane * 2);
            v0 += p.x * c0 + q.x * c1;
            v1 += p.y * c0 + q.y * c1;
        }
        if (e < e1) {
            int s0 = a.esrc[e];
            float c0 = a.coefs[e];
            float2 p = *(const float2*)(a.x + (size_t)s0 * OBS + lane * 2);
            v0 += p.x * c0; v1 += p.y * c0;
        }
        ushort2 o; o.x = f2b(v0); o.y = f2b(v1);
        *(ushort2*)(a.aggbf + (size_t)nd * OBS + lane * 2) = o;
    }
    grid.sync();

    // ===== Phase E: GEMM1 + relu + MFMA epilogue (@M2) -> zacc, grid-stride tiles =====
    {
        ushort* As    = buf;                             // hw [0, 8192)
        ushort* Bs    = buf + 8192;                      // hw [8192, 16384)
        ushort* stage = buf;                             // hw [0, 17408)
        ushort* M2t   = buf + 128 * 136;                 // hw [17408, 19456)
        const int wm = (wv & 1) * 64, wn = (wv >> 1) * 32;
        const int l16 = lane & 15, kg = (lane >> 4) * 8;
        const int rs = t >> 3;                           // 0..63
        const int cs = (t & 7) * 8;                      // halves, 16B chunks

        for (int tile = blk; tile < 79 * 8; tile += NB) {
            int bm = tile % 79, bn = tile / 79;
            if (t < 128) {                               // stage M2 chunk transposed
                ushort4 u = *(const ushort4*)(a.M2bf + (size_t)(bn * 128 + t) * ACTD);
                ushort4 w = *(const ushort4*)(a.M2bf + (size_t)(bn * 128 + t) * ACTD + 4);
                M2t[0 * 128 + t] = u.x; M2t[1 * 128 + t] = u.y;
                M2t[2 * 128 + t] = u.z; M2t[3 * 128 + t] = u.w;
                M2t[4 * 128 + t] = w.x; M2t[5 * 128 + t] = w.y;
                M2t[6 * 128 + t] = w.z; M2t[7 * 128 + t] = w.w;
                #pragma unroll
                for (int j = 8; j < 16; ++j) M2t[j * 128 + t] = 0;
            }
            f32x4 acc[4][2];
            #pragma unroll
            for (int i = 0; i < 4; ++i)
                #pragma unroll
                for (int j = 0; j < 2; ++j)
                    acc[i][j] = (f32x4){0.f, 0.f, 0.f, 0.f};

            #pragma unroll
            for (int kt = 0; kt < OBS; kt += 64) {
                #pragma unroll
                for (int p = 0; p < 2; ++p) {            // 64 rows/pass
                    int r = rs + p * 64;
                    int gr = bm * 128 + r; if (gr >= NNODES) gr = NNODES - 1;
                    __builtin_amdgcn_global_load_lds(
                        (gl_u32*)(a.aggbf + (size_t)gr * OBS + kt + cs),
                        (lds_u32*)(As + r * 64 + cs), 16, 0, 0);
                    int gn = bn * 128 + r;
                    __builtin_amdgcn_global_load_lds(
                        (gl_u32*)(a.Wt1 + (size_t)gn * OBS + kt + cs),
                        (lds_u32*)(Bs + r * 64 + cs), 16, 0, 0);
                }
                __syncthreads();
                #pragma unroll
                for (int k2 = 0; k2 < 64; k2 += 32) {
                    bf16x8 af[4], bfr[2];
                    #pragma unroll
                    for (int i = 0; i < 4; ++i)
                        af[i] = *(const bf16x8*)(As + (wm + i * 16 + l16) * 64 + k2 + kg);
                    #pragma unroll
                    for (int j = 0; j < 2; ++j)
                        bfr[j] = *(const bf16x8*)(Bs + (wn + j * 16 + l16) * 64 + k2 + kg);
                    #pragma unroll
                    for (int i = 0; i < 4; ++i)
                        #pragma unroll
                        for (int j = 0; j < 2; ++j)
                            acc[i][j] = __builtin_amdgcn_mfma_f32_16x16x32_bf16(af[i], bfr[j], acc[i][j], 0, 0, 0);
                }
                __syncthreads();
            }

            // relu(acc + b1) -> stage bf16; C/D layout: col=lane&15, row=(lane>>4)*4+reg
            #pragma unroll
            for (int i = 0; i < 4; ++i) {
                int rowb = wm + i * 16 + (lane >> 4) * 4;
                #pragma unroll
                for (int j = 0; j < 2; ++j) {
                    int col = wn + j * 16 + l16;
                    float bj = a.b1[bn * 128 + col];
                    #pragma unroll
                    for (int r = 0; r < 4; ++r)
                        stage[(rowb + r) * 136 + col] = f2b(fmaxf(acc[i][j][r] + bj, 0.0f));
                }
            }
            __syncthreads();

            // stage[128x128] @ M2t^T -> zacc (16 rows per wave)
            {
                int row0 = wv * 16;
                f32x4 z = (f32x4){0.f, 0.f, 0.f, 0.f};
                #pragma unroll
                for (int kt = 0; kt < 128; kt += 32) {
                    bf16x8 aa = *(const bf16x8*)(stage + (row0 + l16) * 136 + kt + kg);
                    bf16x8 bb = *(const bf16x8*)(M2t + l16 * 128 + kt + kg);
                    z = __builtin_amdgcn_mfma_f32_16x16x32_bf16(aa, bb, z, 0, 0, 0);
                }
                if (l16 < ACTD) {
                    int rowb = bm * 128 + row0 + (lane >> 4) * 4;
                    #pragma unroll
                    for (int r = 0; r < 4; ++r)
                        if (rowb + r < NNODES)
                            atomicAdd(&a.zacc[(size_t)(rowb + r) * ACTD + l16], z[r]);
                }
            }
            __syncthreads();                             // protect stage/M2t for next tile
        }
    }
    grid.sync();

    // ===== Phase F: z-aggregation (gather) + tanh + hierarchical pool =====
    {
        float* part  = (float*)buf;                      // 512 f32
        int*   partc = (int*)(buf + 1024);               // 64 ints (byte off 2048)
        if (t < NGR * ACTD) part[t] = 0.0f;
        if (t < NGR) partc[t] = 0;
        __syncthreads();
        int i0 = blk * 40;                               // 250 blocks cover 10000
        bool active = i0 < NNODES;
        if (active && t < 40 * ACTD) {
            int i = i0 + (t >> 3), j = t & 7;
            if (i < NNODES) {
                float d = a.dinv[i];
                float v = a.zacc[(size_t)i * ACTD + j] * d * d;
                int e0 = a.rowptr[i], e1 = a.rowptr[i + 1];
                for (int e = e0; e < e1; ++e)
                    v += a.coefs[e] * a.zacc[(size_t)a.esrc[e] * ACTD + j];
                float tz = tanhf(v + a.b2l[j]);
                int g = cix(a.bat[i], NGR);
                atomicAdd(&part[g * ACTD + j], tz);
                if (j == 0) atomicAdd(&partc[g], 1);
            }
        }
        __syncthreads();
        if (active) {
            int i1 = i0 + 39; if (i1 >= NNODES) i1 = NNODES - 1;
            int g0 = cix(a.bat[i0], NGR), g1 = cix(a.bat[i1], NGR);
            int ng = g1 - g0 + 1;                        // sorted batch => contiguous
            if (t < ng * ACTD)
                atomicAdd(&a.pool[g0 * ACTD + t], part[g0 * ACTD + t]);
            if (t < ng) {
                int c = partc[g0 + t];
                if (c) atomicAdd(&a.cnt[g0 + t], (float)c);
            }
        }
    }
    grid.sync();

    // ===== Phase G: finalize output =====
    if (blk == 0 && t < NGR * ACTD)
        a.out[t] = a.pool[t] / fmaxf(a.cnt[t >> 3], 1.0f);
}

// ---------- launch ----------
extern "C" void kernel_launch(void* const* d_in, const int* in_sizes, int n_in,
                              void* d_out, int out_size, void* d_ws, size_t ws_size,
                              hipStream_t stream) {
    const float* x   = (const float*)d_in[0];
    const int*   ei  = (const int*)d_in[1];
    const int*   bat = (const int*)d_in[2];
    const float* W1  = (const float*)d_in[3];
    const float* b1  = (const float*)d_in[4];
    const float* W2  = (const float*)d_in[5];
    const float* b2v = (const float*)d_in[6];
    const float* Wl  = (const float*)d_in[7];
    const float* bl  = (const float*)d_in[8];
    float* out = (float*)d_out;

    // workspace layout — zero-init region first (single memset), ~4.0 MB total
    char* ws = (char*)d_ws;
    size_t off = 0;
    float*  pool   = (float*)(ws + off); off += 2048;                    // 512 f32
    float*  cnt    = (float*)(ws + off); off += 256;                     // 64 f32
    float*  zacc   = (float*)(ws + off); off += (size_t)NNODES * ACTD * 4; // 320000
    int*    degi   = (int*)(ws + off);   off += 40192;                   // N i32
    const size_t ZEROSZ = off;                                           // 362496 B
    float*  dinv   = (float*)(ws + off); off += 40192;
    int*    rowptr = (int*)(ws + off);   off += 40448;
    int*    cursor = (int*)(ws + off);   off += 40192;
    int*    esrc   = (int*)(ws + off);   off += (size_t)NEDGES * 4;
    float*  coefs  = (float*)(ws + off); off += (size_t)NEDGES * 4;
    float*  b2l    = (float*)(ws + off); off += 256;
    ushort* M2bf   = (ushort*)(ws + off); off += (size_t)HID * ACTD * 2;
    ushort* Wt1    = (ushort*)(ws + off); off += (size_t)HID * OBS * 2;
    ushort* aggbf  = (ushort*)(ws + off); off += (size_t)NNODES * OBS * 2;

    hipMemsetAsync(d_ws, 0, ZEROSZ, stream);

    MegaArgs ar;
    ar.x = x; ar.src = ei; ar.dst = ei + NEDGES; ar.bat = bat;
    ar.W1 = W1; ar.b1 = b1; ar.W2 = W2; ar.b2 = b2v; ar.Wl = Wl; ar.bl = bl;
    ar.out = out;
    ar.pool = pool; ar.cnt = cnt; ar.zacc = zacc; ar.degi = degi;
    ar.dinv = dinv; ar.rowptr = rowptr; ar.cursor = cursor;
    ar.esrc = esrc; ar.coefs = coefs;
    ar.b2l = b2l; ar.M2bf = M2bf; ar.Wt1 = Wt1; ar.aggbf = aggbf;

    void* kparams[] = { &ar };
    hipLaunchCooperativeKernel((const void*)k_mega, dim3(NB), dim3(NT),
                               kparams, 0, stream);
}

// Round 10
// 138.296 us; speedup vs baseline: 2.4030x; 2.4030x over previous
//
#include <hip/hip_runtime.h>
#include <hip/hip_bf16.h>

// ---------- constants (problem-fixed) ----------
#define NNODES 10000
#define NEDGES 80000
#define OBS    128
#define HID    1024
#define ACTD   8
#define NGR    64

typedef __bf16 bf16x8 __attribute__((ext_vector_type(8)));
typedef float  f32x4  __attribute__((ext_vector_type(4)));
typedef const __attribute__((address_space(1))) unsigned int gl_u32;
typedef __attribute__((address_space(3))) unsigned int lds_u32;

__device__ __forceinline__ ushort f2b(float f) {       // f32 -> bf16 (RNE)
    union { float f; unsigned int i; } v; v.f = f;
    unsigned int lsb = (v.i >> 16) & 1u;
    unsigned int r = v.i + 0x7fffu + lsb;
    return (ushort)(r >> 16);
}
__device__ __forceinline__ int cix(int v, int hi) {    // clamp index to [0, hi)
    return v < 0 ? 0 : (v >= hi ? hi - 1 : v);
}

// ---------- fused prep: zero accumulators + weight prep, block-partitioned ----------
//  blocks [0,128):   transpose+cast W1 [OBS x HID] -> Wt1 [HID x OBS] bf16
//  blocks [128,385): M2bf[i][:] = bf16(W2[i,:] @ Wl); row HID -> b2l = b2@Wl + bl
//  blocks [385,698): zero zacc / pool / cnt / ticket / degi
__global__ __launch_bounds__(256) void k_prep(const float* __restrict__ W1,
                                              const float* __restrict__ W2,
                                              const float* __restrict__ Wl,
                                              const float* __restrict__ b2,
                                              const float* __restrict__ bl,
                                              ushort* __restrict__ Wt1,
                                              ushort* __restrict__ M2bf,
                                              float* __restrict__ b2l,
                                              float* __restrict__ zacc,
                                              float* __restrict__ pool,
                                              float* __restrict__ cnt,
                                              int* __restrict__ ticket,
                                              int* __restrict__ degi) {
    int blk = blockIdx.x;
    if (blk >= 385) {
        int idx = (blk - 385) * 256 + threadIdx.x;
        if (idx < NNODES * ACTD) zacc[idx] = 0.0f;
        if (idx < NGR * ACTD) pool[idx] = 0.0f;
        if (idx < NGR) cnt[idx] = 0.0f;
        if (idx < NNODES) degi[idx] = 0;
        if (idx == 0) *ticket = 0;
        return;
    }
    if (blk < 128) {
        __shared__ float tile[32][33];
        int bx = (blk & 31) * 32, by = (blk >> 5) * 32;  // bx over HID, by over OBS
        int tx = threadIdx.x & 31, ty = threadIdx.x >> 5;
        #pragma unroll
        for (int i = 0; i < 32; i += 8)
            tile[ty + i][tx] = W1[(size_t)(by + ty + i) * HID + bx + tx];
        __syncthreads();
        #pragma unroll
        for (int i = 0; i < 32; i += 8)
            Wt1[(size_t)(bx + ty + i) * OBS + by + tx] = f2b(tile[tx][ty + i]);
        return;
    }
    int wvid = ((blk - 128) * 256 + (int)threadIdx.x) >> 6;
    int lane = threadIdx.x & 63;
    if (wvid > HID) return;
    const float* row = (wvid == HID) ? b2 : (W2 + (size_t)wvid * HID);
    float acc[ACTD];
    #pragma unroll
    for (int j = 0; j < ACTD; ++j) acc[j] = 0.0f;
    for (int it = 0; it < HID / 64; ++it) {
        int k = it * 64 + lane;
        float w2v = row[k];
        float4 a = *(const float4*)(Wl + (size_t)k * ACTD);
        float4 b = *(const float4*)(Wl + (size_t)k * ACTD + 4);
        acc[0] += w2v * a.x; acc[1] += w2v * a.y; acc[2] += w2v * a.z; acc[3] += w2v * a.w;
        acc[4] += w2v * b.x; acc[5] += w2v * b.y; acc[6] += w2v * b.z; acc[7] += w2v * b.w;
    }
    #pragma unroll
    for (int off = 32; off > 0; off >>= 1)
        #pragma unroll
        for (int j = 0; j < ACTD; ++j)
            acc[j] += __shfl_down(acc[j], off);
    if (lane == 0) {
        if (wvid == HID) {
            #pragma unroll
            for (int j = 0; j < ACTD; ++j) b2l[j] = acc[j] + bl[j];
        } else {
            #pragma unroll
            for (int j = 0; j < ACTD; ++j) M2bf[wvid * ACTD + j] = f2b(acc[j]);
        }
    }
}

__global__ void k_count(const int* __restrict__ dst, int* degi, int e) {
    int i = blockIdx.x * 256 + threadIdx.x;
    if (i < e) atomicAdd(&degi[cix(dst[i], NNODES)], 1);
}

// single-block scan via wave shuffles (2 barriers) -> rowptr (N+1) + cursor + dinv
__global__ __launch_bounds__(1024) void k_scan(const int* __restrict__ degi,
                                               int* rowptr, int* cursor, float* dinv) {
    __shared__ int wsum[16];
    int t = threadIdx.x, lane = t & 63, w = t >> 6;
    int base = t * 10;                                   // 10240 >= NNODES
    int local[10];
    int s = 0;
    #pragma unroll
    for (int k = 0; k < 10; ++k) {
        int i = base + k;
        int v = 0;
        if (i < NNODES) {
            v = degi[i];
            dinv[i] = rsqrtf((float)(v + 1));            // +1 self-loop
        }
        local[k] = s; s += v;
    }
    int sc = s;                                          // inclusive wave scan
    #pragma unroll
    for (int off = 1; off < 64; off <<= 1) {
        int u = __shfl_up(sc, off);
        if (lane >= off) sc += u;
    }
    if (lane == 63) wsum[w] = sc;
    __syncthreads();
    if (w == 0 && lane < 16) {
        int v = wsum[lane];
        #pragma unroll
        for (int off = 1; off < 16; off <<= 1) {
            int u = __shfl_up(v, off);
            if (lane >= off) v += u;
        }
        wsum[lane] = v;
    }
    __syncthreads();
    int excl = ((w == 0) ? 0 : wsum[w - 1]) + (sc - s);
    #pragma unroll
    for (int k = 0; k < 10; ++k) {
        int i = base + k;
        if (i < NNODES) { rowptr[i] = excl + local[k]; cursor[i] = excl + local[k]; }
    }
    if (t == 0) rowptr[NNODES] = wsum[15];
}

// bucket edges by dst: one 8-B record {src, coef} per edge
__global__ void k_fill(const int* __restrict__ src, const int* __restrict__ dst,
                       const float* __restrict__ dinv, int* cursor,
                       int2* __restrict__ epair, int e) {
    int i = blockIdx.x * 256 + threadIdx.x;
    if (i >= e) return;
    int s = cix(src[i], NNODES), d = cix(dst[i], NNODES);
    int pos = atomicAdd(&cursor[d], 1);
    epair[pos] = make_int2(s, __float_as_int(dinv[s] * dinv[d]));
}

// ---------- layer-1 aggregation: CSR gather, wave per node, half-wave float4 ----------
// lanes 0-31 handle even edges, 32-63 odd edges; each lane covers 4 columns (16 B).
__global__ void k_aggx(const float* __restrict__ x, const float* __restrict__ dinv,
                       const int* __restrict__ rowptr, const int2* __restrict__ epair,
                       ushort* __restrict__ aggbf, int n) {
    int wv = (blockIdx.x * 256 + threadIdx.x) >> 6;
    int lane = threadIdx.x & 63;
    if (wv >= n) return;
    int half = lane >> 5, li = lane & 31;
    float acc0 = 0.f, acc1 = 0.f, acc2 = 0.f, acc3 = 0.f;
    if (half == 0) {                                     // self-loop term (lower half)
        float d = dinv[wv], d2 = d * d;
        float4 sv = *((const float4*)(x + (size_t)wv * OBS) + li);
        acc0 = sv.x * d2; acc1 = sv.y * d2; acc2 = sv.z * d2; acc3 = sv.w * d2;
    }
    int e1 = rowptr[wv + 1];
    int e = rowptr[wv] + half;
    for (; e + 2 < e1; e += 4) {                         // 2 edges/half in flight
        int2 p0 = epair[e], p1 = epair[e + 2];
        float c0 = __int_as_float(p0.y), c1 = __int_as_float(p1.y);
        float4 a = *((const float4*)(x + (size_t)p0.x * OBS) + li);
        float4 b = *((const float4*)(x + (size_t)p1.x * OBS) + li);
        acc0 += a.x * c0 + b.x * c1;
        acc1 += a.y * c0 + b.y * c1;
        acc2 += a.z * c0 + b.z * c1;
        acc3 += a.w * c0 + b.w * c1;
    }
    if (e < e1) {
        int2 p0 = epair[e];
        float c0 = __int_as_float(p0.y);
        float4 a = *((const float4*)(x + (size_t)p0.x * OBS) + li);
        acc0 += a.x * c0; acc1 += a.y * c0; acc2 += a.z * c0; acc3 += a.w * c0;
    }
    acc0 += __shfl_down(acc0, 32);                       // combine halves
    acc1 += __shfl_down(acc1, 32);
    acc2 += __shfl_down(acc2, 32);
    acc3 += __shfl_down(acc3, 32);
    if (half == 0) {
        ushort4 o; o.x = f2b(acc0); o.y = f2b(acc1); o.z = f2b(acc2); o.w = f2b(acc3);
        *((ushort4*)(aggbf + (size_t)wv * OBS) + li) = o;
    }
}

// ---------- fused GEMM1 + relu + MFMA epilogue (@M2) -> zacc ----------
// block 256 (4 waves), tile 128x128, K=OBS=128, BK=64, async global->LDS staging.
__global__ __launch_bounds__(256) void k_gemm1_fused(const ushort* __restrict__ A,
                                                     const ushort* __restrict__ Bt,
                                                     const float* __restrict__ bias,
                                                     const ushort* __restrict__ M2bf,
                                                     float* __restrict__ zacc,
                                                     int M) {
    __shared__ ushort buf[128 * 136 + 16 * 128];         // 38912 B
    ushort* As    = buf;                                 // hw [0, 8192)
    ushort* Bs    = buf + 8192;                          // hw [8192, 16384)
    ushort* stage = buf;                                 // hw [0, 17408) after K-loop
    ushort* M2t   = buf + 128 * 136;                     // hw [17408, 19456)

    const int t = threadIdx.x;
    const int bm = blockIdx.x, bn = blockIdx.y;
    const int lane = t & 63, wv = t >> 6;
    const int wm = (wv & 1) * 64, wn = (wv >> 1) * 64;
    const int l16 = lane & 15, kg = (lane >> 4) * 8;

    if (t < 128) {
        ushort4 a = *(const ushort4*)(M2bf + (size_t)(bn * 128 + t) * ACTD);
        ushort4 b = *(const ushort4*)(M2bf + (size_t)(bn * 128 + t) * ACTD + 4);
        M2t[0 * 128 + t] = a.x; M2t[1 * 128 + t] = a.y;
        M2t[2 * 128 + t] = a.z; M2t[3 * 128 + t] = a.w;
        M2t[4 * 128 + t] = b.x; M2t[5 * 128 + t] = b.y;
        M2t[6 * 128 + t] = b.z; M2t[7 * 128 + t] = b.w;
        #pragma unroll
        for (int j = 8; j < 16; ++j) M2t[j * 128 + t] = 0;
    }

    f32x4 acc[4][4];
    #pragma unroll
    for (int i = 0; i < 4; ++i)
        #pragma unroll
        for (int j = 0; j < 4; ++j)
            acc[i][j] = (f32x4){0.f, 0.f, 0.f, 0.f};

    const int rs = t >> 3;                               // 0..31
    const int cs = (t & 7) * 8;                          // hw col, 16B chunks
    #pragma unroll
    for (int kt = 0; kt < OBS; kt += 64) {
        #pragma unroll
        for (int p = 0; p < 4; ++p) {                    // 32 rows/pass
            int r = rs + p * 32;
            int gr = bm * 128 + r; if (gr >= M) gr = M - 1;   // clamp (row discarded later)
            __builtin_amdgcn_global_load_lds(
                (gl_u32*)(A + (size_t)gr * OBS + kt + cs),
                (lds_u32*)(As + r * 64 + cs), 16, 0, 0);
            int gn = bn * 128 + r;
            __builtin_amdgcn_global_load_lds(
                (gl_u32*)(Bt + (size_t)gn * OBS + kt + cs),
                (lds_u32*)(Bs + r * 64 + cs), 16, 0, 0);
        }
        __syncthreads();
        #pragma unroll
        for (int k2 = 0; k2 < 64; k2 += 32) {
            bf16x8 af[4], bfr[4];
            #pragma unroll
            for (int i = 0; i < 4; ++i)
                af[i] = *(const bf16x8*)(As + (wm + i * 16 + l16) * 64 + k2 + kg);
            #pragma unroll
            for (int j = 0; j < 4; ++j)
                bfr[j] = *(const bf16x8*)(Bs + (wn + j * 16 + l16) * 64 + k2 + kg);
            #pragma unroll
            for (int i = 0; i < 4; ++i)
                #pragma unroll
                for (int j = 0; j < 4; ++j)
                    acc[i][j] = __builtin_amdgcn_mfma_f32_16x16x32_bf16(af[i], bfr[j], acc[i][j], 0, 0, 0);
        }
        __syncthreads();
    }

    #pragma unroll
    for (int i = 0; i < 4; ++i) {
        int rowb = wm + i * 16 + (lane >> 4) * 4;
        #pragma unroll
        for (int j = 0; j < 4; ++j) {
            int col = wn + j * 16 + l16;
            float bj = bias[bn * 128 + col];
            #pragma unroll
            for (int r = 0; r < 4; ++r)
                stage[(rowb + r) * 136 + col] = f2b(fmaxf(acc[i][j][r] + bj, 0.0f));
        }
    }
    __syncthreads();

    #pragma unroll
    for (int st = 0; st < 2; ++st) {
        int row0 = wv * 32 + st * 16;
        f32x4 z = (f32x4){0.f, 0.f, 0.f, 0.f};
        #pragma unroll
        for (int kt = 0; kt < 128; kt += 32) {
            bf16x8 a = *(const bf16x8*)(stage + (row0 + l16) * 136 + kt + kg);
            bf16x8 b = *(const bf16x8*)(M2t + l16 * 128 + kt + kg);
            z = __builtin_amdgcn_mfma_f32_16x16x32_bf16(a, b, z, 0, 0, 0);
        }
        if (l16 < ACTD) {
            int rowb = bm * 128 + row0 + (lane >> 4) * 4;
            #pragma unroll
            for (int r = 0; r < 4; ++r)
                if (rowb + r < M)
                    atomicAdd(&zacc[(size_t)(rowb + r) * ACTD + l16], z[r]);
        }
    }
}

// ---------- z-aggregation (gather) + tanh + hierarchical pool + last-block finalize ----------
__global__ __launch_bounds__(1024) void k_zfinal(const float* __restrict__ zacc,
                                                 const float* __restrict__ dinv,
                                                 const int* __restrict__ rowptr,
                                                 const int2* __restrict__ epair,
                                                 const float* __restrict__ b2l,
                                                 const int* __restrict__ batch,
                                                 float* __restrict__ pool,
                                                 float* __restrict__ cnt,
                                                 int* __restrict__ ticket,
                                                 float* __restrict__ out, int n) {
    __shared__ float part[NGR * ACTD];
    __shared__ int   partc[NGR];
    __shared__ int   lastflag;
    int t = threadIdx.x;
    if (t < NGR * ACTD) part[t] = 0.0f;
    if (t < NGR) partc[t] = 0;
    __syncthreads();

    int idx = blockIdx.x * 1024 + t;
    int i = idx >> 3, j = idx & 7;
    if (i < n) {
        float d = dinv[i];
        float v = zacc[idx] * d * d;
        int e0 = rowptr[i], e1 = rowptr[i + 1];
        for (int e = e0; e < e1; ++e) {
            int2 p = epair[e];
            v += __int_as_float(p.y) * zacc[(size_t)p.x * ACTD + j];
        }
        float tz = tanhf(v + b2l[j]);
        int g = cix(batch[i], NGR);
        atomicAdd(&part[g * ACTD + j], tz);
        if (j == 0) atomicAdd(&partc[g], 1);
    }
    __syncthreads();

    int i0 = (blockIdx.x * 1024) >> 3;
    int i1 = (blockIdx.x * 1024 + 1023) >> 3;
    if (i0 < n) {
        if (i1 >= n) i1 = n - 1;
        int g0 = cix(batch[i0], NGR), g1 = cix(batch[i1], NGR);
        int ng = g1 - g0 + 1;                            // sorted batch => contiguous
        if (t < ng * ACTD)
            atomicAdd(&pool[g0 * ACTD + t], part[g0 * ACTD + t]);
        if (t < ng) {
            int c = partc[g0 + t];
            if (c) atomicAdd(&cnt[g0 + t], (float)c);
        }
    }
    // last block to finish flushing finalizes the output
    __syncthreads();
    if (t == 0) {
        __threadfence();                                 // release our pool atomics
        int old = atomicAdd(ticket, 1);
        lastflag = (old == (int)gridDim.x - 1);
    }
    __syncthreads();
    if (lastflag && t < NGR * ACTD) {
        float pv = atomicAdd(&pool[t], 0.0f);            // coherent-point read
        float cv = atomicAdd(&cnt[t >> 3], 0.0f);
        out[t] = pv / fmaxf(cv, 1.0f);
    }
}

// ---------- launch ----------
extern "C" void kernel_launch(void* const* d_in, const int* in_sizes, int n_in,
                              void* d_out, int out_size, void* d_ws, size_t ws_size,
                              hipStream_t stream) {
    const float* x   = (const float*)d_in[0];
    const int*   ei  = (const int*)d_in[1];
    const int*   bat = (const int*)d_in[2];
    const float* W1  = (const float*)d_in[3];
    const float* b1  = (const float*)d_in[4];
    const float* W2  = (const float*)d_in[5];
    const float* b2v = (const float*)d_in[6];
    const float* Wl  = (const float*)d_in[7];
    const float* bl  = (const float*)d_in[8];
    float* out = (float*)d_out;

    const int N = NNODES, E = NEDGES;
    const int* src = ei;
    const int* dst = ei + E;

    // workspace layout — ~4.3 MB total (all offsets multiples of 256 B)
    char* ws = (char*)d_ws;
    size_t off = 0;
    float*  pool   = (float*)(ws + off); off += 2048;
    float*  cnt    = (float*)(ws + off); off += 256;
    int*    ticket = (int*)(ws + off);   off += 256;
    float*  dinv   = (float*)(ws + off); off += 40192;                   // N f32
    int*    degi   = (int*)(ws + off);   off += 40192;                   // N i32
    int*    rowptr = (int*)(ws + off);   off += 40448;                   // N+1 i32
    int*    cursor = (int*)(ws + off);   off += 40192;                   // N i32
    int2*   epair  = (int2*)(ws + off);  off += (size_t)E * 8;           // 640000
    float*  b2l    = (float*)(ws + off); off += 256;
    ushort* M2bf   = (ushort*)(ws + off); off += (size_t)HID * ACTD * 2; // 16384
    ushort* Wt1    = (ushort*)(ws + off); off += (size_t)HID * OBS * 2;  // 262144
    float*  zacc   = (float*)(ws + off); off += (size_t)N * ACTD * 4;    // 320000
    ushort* aggbf  = (ushort*)(ws + off); off += (size_t)N * OBS * 2;    // 2560000

    // 1. fused zero + weight prep
    k_prep<<<698, 256, 0, stream>>>(W1, W2, Wl, b2v, bl, Wt1, M2bf, b2l,
                                    zacc, pool, cnt, ticket, degi);
    // 2-4. degree, scan(+dinv), CSR fill
    k_count<<<(E + 255) / 256, 256, 0, stream>>>(dst, degi, E);
    k_scan<<<1, 1024, 0, stream>>>(degi, rowptr, cursor, dinv);
    k_fill<<<(E + 255) / 256, 256, 0, stream>>>(src, dst, dinv, cursor, epair, E);

    // 5. layer-1 aggregation (gather) -> bf16
    k_aggx<<<(N * 64 + 255) / 256, 256, 0, stream>>>(x, dinv, rowptr, epair, aggbf, N);

    // 6. fused GEMM1 + relu + @M2 -> zacc
    k_gemm1_fused<<<dim3((N + 127) / 128, HID / 128), 256, 0, stream>>>(
        aggbf, Wt1, b1, M2bf, zacc, N);

    // 7. z-aggregation + tanh + hierarchical pool + last-block finalize
    k_zfinal<<<(N * ACTD + 1023) / 1024, 1024, 0, stream>>>(
        zacc, dinv, rowptr, epair, b2l, bat, pool, cnt, ticket, out, N);
}

// Round 11
// 136.568 us; speedup vs baseline: 2.4334x; 1.0127x over previous
//
#include <hip/hip_runtime.h>
#include <hip/hip_bf16.h>

// ---------- constants (problem-fixed) ----------
#define NNODES 10000
#define NEDGES 80000
#define OBS    128
#define HID    1024
#define ACTD   8
#define NGR    64

typedef __bf16 bf16x8 __attribute__((ext_vector_type(8)));
typedef float  f32x4  __attribute__((ext_vector_type(4)));
typedef const __attribute__((address_space(1))) unsigned int gl_u32;
typedef __attribute__((address_space(3))) unsigned int lds_u32;

__device__ __forceinline__ ushort f2b(float f) {       // f32 -> bf16 (RNE)
    union { float f; unsigned int i; } v; v.f = f;
    unsigned int lsb = (v.i >> 16) & 1u;
    unsigned int r = v.i + 0x7fffu + lsb;
    return (ushort)(r >> 16);
}
__device__ __forceinline__ float b2f(ushort u) {
    union { unsigned int i; float f; } v; v.i = ((unsigned int)u) << 16; return v.f;
}
__device__ __forceinline__ int cix(int v, int hi) {    // clamp index to [0, hi)
    return v < 0 ? 0 : (v >= hi ? hi - 1 : v);
}

// ---------- fused prep (zero-init done by hipMemsetAsync beforehand) ----------
//  blk [0,128):     transpose+cast W1 [OBS x HID] -> Wt1 [HID x OBS] bf16
//  blk [128,385):   M2bf[i][:] = bf16(W2[i,:] @ Wl); row HID -> b2l = b2@Wl + bl
//  blk [385,449):   degree count (atomics into zeroed degi)
//  blk [449,1074):  cast x -> xbf (bf16 gather table, 2.56 MB, L2-resident)
__global__ __launch_bounds__(256) void k_prep(const float* __restrict__ W1,
                                              const float* __restrict__ W2,
                                              const float* __restrict__ Wl,
                                              const float* __restrict__ b2,
                                              const float* __restrict__ bl,
                                              const float* __restrict__ x,
                                              const int* __restrict__ dst,
                                              ushort* __restrict__ Wt1,
                                              ushort* __restrict__ M2bf,
                                              float* __restrict__ b2l,
                                              int* __restrict__ degi,
                                              ushort* __restrict__ xbf) {
    int blk = blockIdx.x;
    if (blk >= 449) {                                    // x -> bf16 table
        int idx = (blk - 449) * 256 + threadIdx.x;       // [0, 160000)
        const float4* p = (const float4*)x + (size_t)idx * 2;
        float4 a = p[0], b = p[1];
        uint4 o;
        o.x = (unsigned)f2b(a.x) | ((unsigned)f2b(a.y) << 16);
        o.y = (unsigned)f2b(a.z) | ((unsigned)f2b(a.w) << 16);
        o.z = (unsigned)f2b(b.x) | ((unsigned)f2b(b.y) << 16);
        o.w = (unsigned)f2b(b.z) | ((unsigned)f2b(b.w) << 16);
        *((uint4*)xbf + idx) = o;
        return;
    }
    if (blk >= 385) {                                    // degree count
        for (int i = (blk - 385) * 256 + threadIdx.x; i < NEDGES; i += 64 * 256)
            atomicAdd(&degi[cix(dst[i], NNODES)], 1);
        return;
    }
    if (blk < 128) {                                     // W1 transpose
        __shared__ float tile[32][33];
        int bx = (blk & 31) * 32, by = (blk >> 5) * 32;  // bx over HID, by over OBS
        int tx = threadIdx.x & 31, ty = threadIdx.x >> 5;
        #pragma unroll
        for (int i = 0; i < 32; i += 8)
            tile[ty + i][tx] = W1[(size_t)(by + ty + i) * HID + bx + tx];
        __syncthreads();
        #pragma unroll
        for (int i = 0; i < 32; i += 8)
            Wt1[(size_t)(bx + ty + i) * OBS + by + tx] = f2b(tile[tx][ty + i]);
        return;
    }
    int wvid = ((blk - 128) * 256 + (int)threadIdx.x) >> 6;
    int lane = threadIdx.x & 63;
    if (wvid > HID) return;
    const float* row = (wvid == HID) ? b2 : (W2 + (size_t)wvid * HID);
    float acc[ACTD];
    #pragma unroll
    for (int j = 0; j < ACTD; ++j) acc[j] = 0.0f;
    for (int it = 0; it < HID / 64; ++it) {
        int k = it * 64 + lane;
        float w2v = row[k];
        float4 a = *(const float4*)(Wl + (size_t)k * ACTD);
        float4 b = *(const float4*)(Wl + (size_t)k * ACTD + 4);
        acc[0] += w2v * a.x; acc[1] += w2v * a.y; acc[2] += w2v * a.z; acc[3] += w2v * a.w;
        acc[4] += w2v * b.x; acc[5] += w2v * b.y; acc[6] += w2v * b.z; acc[7] += w2v * b.w;
    }
    #pragma unroll
    for (int off = 32; off > 0; off >>= 1)
        #pragma unroll
        for (int j = 0; j < ACTD; ++j)
            acc[j] += __shfl_down(acc[j], off);
    if (lane == 0) {
        if (wvid == HID) {
            #pragma unroll
            for (int j = 0; j < ACTD; ++j) b2l[j] = acc[j] + bl[j];
        } else {
            #pragma unroll
            for (int j = 0; j < ACTD; ++j) M2bf[wvid * ACTD + j] = f2b(acc[j]);
        }
    }
}

// single-block scan via wave shuffles (2 barriers) -> rowptr (N+1) + cursor + dinv
__global__ __launch_bounds__(1024) void k_scan(const int* __restrict__ degi,
                                               int* rowptr, int* cursor, float* dinv) {
    __shared__ int wsum[16];
    int t = threadIdx.x, lane = t & 63, w = t >> 6;
    int base = t * 10;                                   // 10240 >= NNODES
    int local[10];
    int s = 0;
    #pragma unroll
    for (int k = 0; k < 10; ++k) {
        int i = base + k;
        int v = 0;
        if (i < NNODES) {
            v = degi[i];
            dinv[i] = rsqrtf((float)(v + 1));            // +1 self-loop
        }
        local[k] = s; s += v;
    }
    int sc = s;                                          // inclusive wave scan
    #pragma unroll
    for (int off = 1; off < 64; off <<= 1) {
        int u = __shfl_up(sc, off);
        if (lane >= off) sc += u;
    }
    if (lane == 63) wsum[w] = sc;
    __syncthreads();
    if (w == 0 && lane < 16) {
        int v = wsum[lane];
        #pragma unroll
        for (int off = 1; off < 16; off <<= 1) {
            int u = __shfl_up(v, off);
            if (lane >= off) v += u;
        }
        wsum[lane] = v;
    }
    __syncthreads();
    int excl = ((w == 0) ? 0 : wsum[w - 1]) + (sc - s);
    #pragma unroll
    for (int k = 0; k < 10; ++k) {
        int i = base + k;
        if (i < NNODES) { rowptr[i] = excl + local[k]; cursor[i] = excl + local[k]; }
    }
    if (t == 0) rowptr[NNODES] = wsum[15];
}

// bucket edges by dst: one 8-B record {src, coef} per edge
__global__ void k_fill(const int* __restrict__ src, const int* __restrict__ dst,
                       const float* __restrict__ dinv, int* cursor,
                       int2* __restrict__ epair, int e) {
    int i = blockIdx.x * 256 + threadIdx.x;
    if (i >= e) return;
    int s = cix(src[i], NNODES), d = cix(dst[i], NNODES);
    int pos = atomicAdd(&cursor[d], 1);
    epair[pos] = make_int2(s, __float_as_int(dinv[s] * dinv[d]));
}

// ---------- layer-1 aggregation: CSR gather from bf16 x-table, wave per node ----------
// lanes 0-31 even edges, 32-63 odd edges; each lane covers 4 columns (8 B bf16).
__global__ void k_aggx(const float* __restrict__ x, const ushort* __restrict__ xbf,
                       const float* __restrict__ dinv,
                       const int* __restrict__ rowptr, const int2* __restrict__ epair,
                       ushort* __restrict__ aggbf, int n) {
    int wv = (blockIdx.x * 256 + threadIdx.x) >> 6;
    int lane = threadIdx.x & 63;
    if (wv >= n) return;
    int half = lane >> 5, li = lane & 31;
    float acc0 = 0.f, acc1 = 0.f, acc2 = 0.f, acc3 = 0.f;
    if (half == 0) {                                     // self-loop term, f32 exact
        float d = dinv[wv], d2 = d * d;
        float4 sv = *((const float4*)(x + (size_t)wv * OBS) + li);
        acc0 = sv.x * d2; acc1 = sv.y * d2; acc2 = sv.z * d2; acc3 = sv.w * d2;
    }
    int e1 = rowptr[wv + 1];
    int e = rowptr[wv] + half;
    for (; e + 2 < e1; e += 4) {                         // 2 edges/half in flight
        int2 p0 = epair[e], p1 = epair[e + 2];
        float c0 = __int_as_float(p0.y), c1 = __int_as_float(p1.y);
        ushort4 a = *((const ushort4*)(xbf + (size_t)p0.x * OBS) + li);
        ushort4 b = *((const ushort4*)(xbf + (size_t)p1.x * OBS) + li);
        acc0 += b2f(a.x) * c0 + b2f(b.x) * c1;
        acc1 += b2f(a.y) * c0 + b2f(b.y) * c1;
        acc2 += b2f(a.z) * c0 + b2f(b.z) * c1;
        acc3 += b2f(a.w) * c0 + b2f(b.w) * c1;
    }
    if (e < e1) {
        int2 p0 = epair[e];
        float c0 = __int_as_float(p0.y);
        ushort4 a = *((const ushort4*)(xbf + (size_t)p0.x * OBS) + li);
        acc0 += b2f(a.x) * c0; acc1 += b2f(a.y) * c0;
        acc2 += b2f(a.z) * c0; acc3 += b2f(a.w) * c0;
    }
    acc0 += __shfl_down(acc0, 32);                       // combine halves
    acc1 += __shfl_down(acc1, 32);
    acc2 += __shfl_down(acc2, 32);
    acc3 += __shfl_down(acc3, 32);
    if (half == 0) {
        ushort4 o; o.x = f2b(acc0); o.y = f2b(acc1); o.z = f2b(acc2); o.w = f2b(acc3);
        *((ushort4*)(aggbf + (size_t)wv * OBS) + li) = o;
    }
}

// ---------- fused GEMM1 + relu + MFMA epilogue (@M2) -> zacc ----------
// block 256 (4 waves), tile 128x128, K=OBS=128, BK=64, async global->LDS staging.
__global__ __launch_bounds__(256) void k_gemm1_fused(const ushort* __restrict__ A,
                                                     const ushort* __restrict__ Bt,
                                                     const float* __restrict__ bias,
                                                     const ushort* __restrict__ M2bf,
                                                     float* __restrict__ zacc,
                                                     int M) {
    __shared__ ushort buf[128 * 136 + 16 * 128];         // 38912 B
    ushort* As    = buf;                                 // hw [0, 8192)
    ushort* Bs    = buf + 8192;                          // hw [8192, 16384)
    ushort* stage = buf;                                 // hw [0, 17408) after K-loop
    ushort* M2t   = buf + 128 * 136;                     // hw [17408, 19456)

    const int t = threadIdx.x;
    const int bm = blockIdx.x, bn = blockIdx.y;
    const int lane = t & 63, wv = t >> 6;
    const int wm = (wv & 1) * 64, wn = (wv >> 1) * 64;
    const int l16 = lane & 15, kg = (lane >> 4) * 8;

    if (t < 128) {
        ushort4 a = *(const ushort4*)(M2bf + (size_t)(bn * 128 + t) * ACTD);
        ushort4 b = *(const ushort4*)(M2bf + (size_t)(bn * 128 + t) * ACTD + 4);
        M2t[0 * 128 + t] = a.x; M2t[1 * 128 + t] = a.y;
        M2t[2 * 128 + t] = a.z; M2t[3 * 128 + t] = a.w;
        M2t[4 * 128 + t] = b.x; M2t[5 * 128 + t] = b.y;
        M2t[6 * 128 + t] = b.z; M2t[7 * 128 + t] = b.w;
        #pragma unroll
        for (int j = 8; j < 16; ++j) M2t[j * 128 + t] = 0;
    }

    f32x4 acc[4][4];
    #pragma unroll
    for (int i = 0; i < 4; ++i)
        #pragma unroll
        for (int j = 0; j < 4; ++j)
            acc[i][j] = (f32x4){0.f, 0.f, 0.f, 0.f};

    const int rs = t >> 3;                               // 0..31
    const int cs = (t & 7) * 8;                          // hw col, 16B chunks
    #pragma unroll
    for (int kt = 0; kt < OBS; kt += 64) {
        #pragma unroll
        for (int p = 0; p < 4; ++p) {                    // 32 rows/pass
            int r = rs + p * 32;
            int gr = bm * 128 + r; if (gr >= M) gr = M - 1;   // clamp (row discarded later)
            __builtin_amdgcn_global_load_lds(
                (gl_u32*)(A + (size_t)gr * OBS + kt + cs),
                (lds_u32*)(As + r * 64 + cs), 16, 0, 0);
            int gn = bn * 128 + r;
            __builtin_amdgcn_global_load_lds(
                (gl_u32*)(Bt + (size_t)gn * OBS + kt + cs),
                (lds_u32*)(Bs + r * 64 + cs), 16, 0, 0);
        }
        __syncthreads();
        #pragma unroll
        for (int k2 = 0; k2 < 64; k2 += 32) {
            bf16x8 af[4], bfr[4];
            #pragma unroll
            for (int i = 0; i < 4; ++i)
                af[i] = *(const bf16x8*)(As + (wm + i * 16 + l16) * 64 + k2 + kg);
            #pragma unroll
            for (int j = 0; j < 4; ++j)
                bfr[j] = *(const bf16x8*)(Bs + (wn + j * 16 + l16) * 64 + k2 + kg);
            #pragma unroll
            for (int i = 0; i < 4; ++i)
                #pragma unroll
                for (int j = 0; j < 4; ++j)
                    acc[i][j] = __builtin_amdgcn_mfma_f32_16x16x32_bf16(af[i], bfr[j], acc[i][j], 0, 0, 0);
        }
        __syncthreads();
    }

    #pragma unroll
    for (int i = 0; i < 4; ++i) {
        int rowb = wm + i * 16 + (lane >> 4) * 4;
        #pragma unroll
        for (int j = 0; j < 4; ++j) {
            int col = wn + j * 16 + l16;
            float bj = bias[bn * 128 + col];
            #pragma unroll
            for (int r = 0; r < 4; ++r)
                stage[(rowb + r) * 136 + col] = f2b(fmaxf(acc[i][j][r] + bj, 0.0f));
        }
    }
    __syncthreads();

    #pragma unroll
    for (int st = 0; st < 2; ++st) {
        int row0 = wv * 32 + st * 16;
        f32x4 z = (f32x4){0.f, 0.f, 0.f, 0.f};
        #pragma unroll
        for (int kt = 0; kt < 128; kt += 32) {
            bf16x8 a = *(const bf16x8*)(stage + (row0 + l16) * 136 + kt + kg);
            bf16x8 b = *(const bf16x8*)(M2t + l16 * 128 + kt + kg);
            z = __builtin_amdgcn_mfma_f32_16x16x32_bf16(a, b, z, 0, 0, 0);
        }
        if (l16 < ACTD) {
            int rowb = bm * 128 + row0 + (lane >> 4) * 4;
            #pragma unroll
            for (int r = 0; r < 4; ++r)
                if (rowb + r < M)
                    atomicAdd(&zacc[(size_t)(rowb + r) * ACTD + l16], z[r]);
        }
    }
}

// ---------- z-aggregation (gather) + tanh + hierarchical pool + last-block finalize ----------
__global__ __launch_bounds__(1024) void k_zfinal(const float* __restrict__ zacc,
                                                 const float* __restrict__ dinv,
                                                 const int* __restrict__ rowptr,
                                                 const int2* __restrict__ epair,
                                                 const float* __restrict__ b2l,
                                                 const int* __restrict__ batch,
                                                 float* __restrict__ pool,
                                                 float* __restrict__ cnt,
                                                 int* __restrict__ ticket,
                                                 float* __restrict__ out, int n) {
    __shared__ float part[NGR * ACTD];
    __shared__ int   partc[NGR];
    __shared__ int   lastflag;
    int t = threadIdx.x;
    if (t < NGR * ACTD) part[t] = 0.0f;
    if (t < NGR) partc[t] = 0;
    __syncthreads();

    int idx = blockIdx.x * 1024 + t;
    int i = idx >> 3, j = idx & 7;
    if (i < n) {
        float d = dinv[i];
        float v = zacc[idx] * d * d;
        int e0 = rowptr[i], e1 = rowptr[i + 1];
        for (int e = e0; e < e1; ++e) {
            int2 p = epair[e];
            v += __int_as_float(p.y) * zacc[(size_t)p.x * ACTD + j];
        }
        float tz = tanhf(v + b2l[j]);
        int g = cix(batch[i], NGR);
        atomicAdd(&part[g * ACTD + j], tz);
        if (j == 0) atomicAdd(&partc[g], 1);
    }
    __syncthreads();

    int i0 = (blockIdx.x * 1024) >> 3;
    int i1 = (blockIdx.x * 1024 + 1023) >> 3;
    if (i0 < n) {
        if (i1 >= n) i1 = n - 1;
        int g0 = cix(batch[i0], NGR), g1 = cix(batch[i1], NGR);
        int ng = g1 - g0 + 1;                            // sorted batch => contiguous
        if (t < ng * ACTD)
            atomicAdd(&pool[g0 * ACTD + t], part[g0 * ACTD + t]);
        if (t < ng) {
            int c = partc[g0 + t];
            if (c) atomicAdd(&cnt[g0 + t], (float)c);
        }
    }
    __syncthreads();
    if (t == 0) {
        __threadfence();                                 // release our pool atomics
        int old = atomicAdd(ticket, 1);
        lastflag = (old == (int)gridDim.x - 1);
    }
    __syncthreads();
    if (lastflag && t < NGR * ACTD) {
        float pv = atomicAdd(&pool[t], 0.0f);            // coherent-point read
        float cv = atomicAdd(&cnt[t >> 3], 0.0f);
        out[t] = pv / fmaxf(cv, 1.0f);
    }
}

// ---------- launch ----------
extern "C" void kernel_launch(void* const* d_in, const int* in_sizes, int n_in,
                              void* d_out, int out_size, void* d_ws, size_t ws_size,
                              hipStream_t stream) {
    const float* x   = (const float*)d_in[0];
    const int*   ei  = (const int*)d_in[1];
    const int*   bat = (const int*)d_in[2];
    const float* W1  = (const float*)d_in[3];
    const float* b1  = (const float*)d_in[4];
    const float* W2  = (const float*)d_in[5];
    const float* b2v = (const float*)d_in[6];
    const float* Wl  = (const float*)d_in[7];
    const float* bl  = (const float*)d_in[8];
    float* out = (float*)d_out;

    const int N = NNODES, E = NEDGES;
    const int* src = ei;
    const int* dst = ei + E;

    // workspace layout — zero-region first (single memset), ~7 MB total
    char* ws = (char*)d_ws;
    size_t off = 0;
    float*  pool   = (float*)(ws + off); off += 2048;                    // 512 f32
    float*  cnt    = (float*)(ws + off); off += 256;                     // 64 f32
    int*    ticket = (int*)(ws + off);   off += 256;
    float*  zacc   = (float*)(ws + off); off += (size_t)N * ACTD * 4;    // 320000
    int*    degi   = (int*)(ws + off);   off += 40192;                   // N i32
    const size_t ZEROSZ = off;                                           // 362752 B
    float*  dinv   = (float*)(ws + off); off += 40192;
    int*    rowptr = (int*)(ws + off);   off += 40448;
    int*    cursor = (int*)(ws + off);   off += 40192;
    int2*   epair  = (int2*)(ws + off);  off += (size_t)E * 8;           // 640000
    float*  b2l    = (float*)(ws + off); off += 256;
    ushort* M2bf   = (ushort*)(ws + off); off += (size_t)HID * ACTD * 2; // 16384
    ushort* Wt1    = (ushort*)(ws + off); off += (size_t)HID * OBS * 2;  // 262144
    ushort* xbf    = (ushort*)(ws + off); off += (size_t)N * OBS * 2;    // 2560000
    ushort* aggbf  = (ushort*)(ws + off); off += (size_t)N * OBS * 2;    // 2560000

    // 1. zero accumulators (single small memset; graph-capture-safe)
    hipMemsetAsync(d_ws, 0, ZEROSZ, stream);

    // 2. fused prep: W1 transpose | M2/b2l | degree count | x->bf16 table
    k_prep<<<449 + (N * OBS / 8 + 255) / 256, 256, 0, stream>>>(
        W1, W2, Wl, b2v, bl, x, dst, Wt1, M2bf, b2l, degi, xbf);

    // 3-4. scan(+dinv), CSR fill
    k_scan<<<1, 1024, 0, stream>>>(degi, rowptr, cursor, dinv);
    k_fill<<<(E + 255) / 256, 256, 0, stream>>>(src, dst, dinv, cursor, epair, E);

    // 5. layer-1 aggregation (bf16 gather) -> aggbf
    k_aggx<<<(N * 64 + 255) / 256, 256, 0, stream>>>(x, xbf, dinv, rowptr, epair, aggbf, N);

    // 6. fused GEMM1 + relu + @M2 -> zacc
    k_gemm1_fused<<<dim3((N + 127) / 128, HID / 128), 256, 0, stream>>>(
        aggbf, Wt1, b1, M2bf, zacc, N);

    // 7. z-aggregation + tanh + hierarchical pool + last-block finalize
    k_zfinal<<<(N * ACTD + 1023) / 1024, 1024, 0, stream>>>(
        zacc, dinv, rowptr, epair, b2l, bat, pool, cnt, ticket, out, N);
}